// Round 11
// baseline (324.958 us; speedup 1.0000x reference)
//
#include <hip/hip_runtime.h>
#include <math.h>

#define N_SP 3136
#define BN_EPS 1e-5f

typedef __attribute__((ext_vector_type(8))) short short8;
typedef __attribute__((ext_vector_type(4))) float f32x4;

// ws layout (float elements)
#define K_SZ    (16*384*N_SP)            // kq packed u32 (k, bf16 hi|lo<<16)
#define QB_OFF  (K_SZ)                   // qbuf fp32 [b][384][n]
#define QB_SZ   (16*384*N_SP)
#define KVP_OFF (QB_OFF + QB_SZ)
#define KVP_SZ  (16*6*7*64*80)           // per-chunk partials [d][80]
#define KVF_OFF (KVP_OFF + KVP_SZ)
#define KVF_SZ  (16*6*64*64)             // kv fp32 [bh][d][e]
#define KM_OFF  (KVF_OFF + KVF_SZ)
#define KM_SZ   (16*6*64)
#define WH_OFF  (KM_OFF + KM_SZ)         // wh/wl ushort planes
#define WSPLIT_N (2*384*192)
#define PWS_OFF (WH_OFF + WSPLIT_N)      // WSPLIT_N ushorts*2 = WSPLIT_N floats
#define PSH_OFF (PWS_OFF + 384*9)

// both-sides LDS swizzle for k1 B tile
#define FSWZ(n) ((((n) >> 1) ^ ((n) >> 2)) & 7)

__device__ __forceinline__ void bsplit(float f, ushort& h, ushort& l) {
    uint u = __float_as_uint(f);
    uint hr = (u + 0x7FFFu + ((u >> 16) & 1u)) >> 16;
    h = (ushort)hr;
    float fh = __uint_as_float(hr << 16);
    float fl = f - fh;
    uint v = __float_as_uint(fl);
    l = (ushort)((v + 0x7FFFu + ((v >> 16) & 1u)) >> 16);
}

// ---------------- P0: split qk_w into bf16 hi/lo planes; pre-scale pe weights/BN.
__global__ __launch_bounds__(256) void p0_prep(
    const float* __restrict__ qk_w, const float* __restrict__ pe_w,
    const float* __restrict__ pgamma, const float* __restrict__ pbeta,
    const float* __restrict__ pmean, const float* __restrict__ pvar,
    ushort* __restrict__ wh, ushort* __restrict__ wl,
    float* __restrict__ pwsc, float* __restrict__ psh)
{
    int idx = blockIdx.x * 256 + threadIdx.x;
    if (idx < WSPLIT_N) {
        ushort h, l;
        bsplit(qk_w[idx], h, l);
        wh[idx] = h;
        wl[idx] = l;
    }
    if (idx < 384) {
        float sc = pgamma[idx] / sqrtf(pvar[idx] + BN_EPS);
        psh[idx] = pbeta[idx] - pmean[idx] * sc;
        #pragma unroll
        for (int q = 0; q < 9; ++q) pwsc[idx * 9 + q] = pe_w[idx * 9 + q] * sc;
    }
}

// ---------------- K1: qk GEMM via bf16-split MFMA (R9 structure, measured 83us).
// gg=0 -> qbuf fp32; gg=1 -> kq packed u32.
__global__ __launch_bounds__(256) void k1_qk_mfma(
    const float* __restrict__ x, const ushort* __restrict__ wh, const ushort* __restrict__ wl,
    const float* __restrict__ gamma, const float* __restrict__ beta,
    const float* __restrict__ mean, const float* __restrict__ var,
    uint* __restrict__ kq, float* __restrict__ qbuf)
{
    __shared__ __align__(16) ushort Ah[8192];
    __shared__ __align__(16) ushort Al[8192];
    __shared__ __align__(16) ushort Bh[4096];
    __shared__ __align__(16) ushort Bl[4096];

    const int bx = blockIdx.x;           // 49 n-tiles
    const int by = blockIdx.y;           // 3 o-tiles (128 each)
    const int bz = blockIdx.z;           // b*2+g (slowest)
    const int b = bz >> 1, gg = bz & 1;
    const int t = threadIdx.x;
    const int lane = t & 63, wv = t >> 6;
    const int wr = wv >> 1, wc = wv & 1;
    const int lg = lane >> 4, l15 = lane & 15;

    f32x4 acc[4][2];
    #pragma unroll
    for (int m = 0; m < 4; ++m)
        #pragma unroll
        for (int nf = 0; nf < 2; ++nf)
            acc[m][nf] = (f32x4){0.f, 0.f, 0.f, 0.f};

    const float* xg = x + (size_t)(b * 384 + gg * 192) * N_SP + bx * 64;
    const ushort* whg = wh + (gg * 384 + by * 128) * 192;
    const ushort* wlg = wl + (gg * 384 + by * 128) * 192;

    for (int kt = 0; kt < 3; ++kt) {
        #pragma unroll
        for (int li = 0; li < 4; ++li) {
            int c = li * 256 + t;
            int row = c >> 3, kb = c & 7;
            int goff = row * 192 + kt * 64 + kb * 8;
            float4 vh = *(const float4*)(whg + goff);
            float4 vl = *(const float4*)(wlg + goff);
            int ch = (row * 8 + (kb ^ (row & 7))) * 8;
            *(float4*)&Ah[ch] = vh;
            *(float4*)&Al[ch] = vl;
        }
        #pragma unroll
        for (int li = 0; li < 2; ++li) {
            int idx = li * 256 + t;
            int kp = idx >> 4;
            int nq = idx & 15;
            int k0 = kp * 2;
            const float* px = xg + (size_t)(kt * 64 + k0) * N_SP + nq * 4;
            float4 v0 = *(const float4*)px;
            float4 v1 = *(const float4*)(px + N_SP);
            ushort h0[4], l0[4], h1[4], l1[4];
            float a0[4] = {v0.x, v0.y, v0.z, v0.w};
            float a1[4] = {v1.x, v1.y, v1.z, v1.w};
            #pragma unroll
            for (int i = 0; i < 4; ++i) { bsplit(a0[i], h0[i], l0[i]); bsplit(a1[i], h1[i], l1[i]); }
            int kb = k0 >> 3, ks = (k0 & 6) >> 1;
            #pragma unroll
            for (int i = 0; i < 4; ++i) {
                int n = nq * 4 + i;
                int chunk = n * 8 + (kb ^ FSWZ(n));
                ((uint*)Bh)[chunk * 4 + ks] = (uint)h0[i] | ((uint)h1[i] << 16);
                ((uint*)Bl)[chunk * 4 + ks] = (uint)l0[i] | ((uint)l1[i] << 16);
            }
        }
        __syncthreads();
        #pragma unroll
        for (int s = 0; s < 2; ++s) {
            short8 ah[4], al[4], bh[2], bl[2];
            int kb = s * 4 + lg;
            #pragma unroll
            for (int m = 0; m < 4; ++m) {
                int row = wr * 64 + m * 16 + l15;
                int ch = (row * 8 + (kb ^ (row & 7))) * 8;
                ah[m] = *(const short8*)&Ah[ch];
                al[m] = *(const short8*)&Al[ch];
            }
            #pragma unroll
            for (int nf = 0; nf < 2; ++nf) {
                int n = wc * 32 + nf * 16 + l15;
                int ch = (n * 8 + (kb ^ FSWZ(n))) * 8;
                bh[nf] = *(const short8*)&Bh[ch];
                bl[nf] = *(const short8*)&Bl[ch];
            }
            #pragma unroll
            for (int m = 0; m < 4; ++m)
                #pragma unroll
                for (int nf = 0; nf < 2; ++nf) {
                    acc[m][nf] = __builtin_amdgcn_mfma_f32_16x16x32_bf16(ah[m], bh[nf], acc[m][nf], 0, 0, 0);
                    acc[m][nf] = __builtin_amdgcn_mfma_f32_16x16x32_bf16(ah[m], bl[nf], acc[m][nf], 0, 0, 0);
                    acc[m][nf] = __builtin_amdgcn_mfma_f32_16x16x32_bf16(al[m], bh[nf], acc[m][nf], 0, 0, 0);
                }
        }
        __syncthreads();
    }

    float* scs = (float*)Bh;
    float* shs = scs + 128;
    if (t < 128) {
        int ch = gg * 384 + by * 128 + t;
        float sc = gamma[ch] / sqrtf(var[ch] + BN_EPS);
        scs[t] = sc;
        shs[t] = beta[ch] - mean[ch] * sc;
    }
    __syncthreads();

    size_t obase = ((size_t)b * 384 + by * 128) * N_SP + bx * 64 + wc * 32;
    if (gg == 0) {
        #pragma unroll
        for (int m = 0; m < 4; ++m)
            #pragma unroll
            for (int nf = 0; nf < 2; ++nf) {
                #pragma unroll
                for (int r = 0; r < 4; ++r) {
                    int orow = wr * 64 + m * 16 + lg * 4 + r;
                    float v = acc[m][nf][r] * scs[orow] + shs[orow];
                    v = v > 0.f ? v + 1.f : __expf(v);
                    qbuf[obase + (size_t)orow * N_SP + nf * 16 + l15] = v;
                }
            }
    } else {
        #pragma unroll
        for (int m = 0; m < 4; ++m)
            #pragma unroll
            for (int nf = 0; nf < 2; ++nf) {
                #pragma unroll
                for (int r = 0; r < 4; ++r) {
                    int orow = wr * 64 + m * 16 + lg * 4 + r;
                    float v = acc[m][nf][r] * scs[orow] + shs[orow];
                    v = v > 0.f ? v + 1.f : __expf(v);
                    ushort hh, ll;
                    bsplit(v, hh, ll);
                    kq[obase + (size_t)orow * N_SP + nf * 16 + l15] = (uint)hh | ((uint)ll << 16);
                }
            }
    }
}

// ---------------- K2: kv + ksum via MFMA; k from packed u32, v from fp32 x (unchanged).
__global__ __launch_bounds__(256) void k2_kv_mfma(
    const float* __restrict__ x, const uint* __restrict__ kq,
    float* __restrict__ kv_part)
{
    __shared__ __align__(16) ushort Kh[4096], Kl[4096];
    __shared__ __align__(16) ushort Vh[5120], Vl[5120];

    const int chunk = blockIdx.x;      // 7
    const int h = blockIdx.y, b = blockIdx.z;
    const int t = threadIdx.x;
    const int lane = t & 63, wv = t >> 6;
    const int lg = lane >> 4, l15 = lane & 15;

    const uint* kp  = kq + (size_t)(b*384 + h*64) * N_SP;
    const float* vp = x  + (size_t)(b*384 + h*64) * N_SP;

    #pragma unroll
    for (int li = 0; li < 4; ++li) {
        int idx = li * 256 + t;
        int row = 64 + (idx >> 6), col = idx & 63;
        int off = (row * 8 + ((col >> 3) ^ (row & 7))) * 8 + (col & 7);
        Vh[off] = (row == 64) ? (ushort)0x3F80 : (ushort)0;
        Vl[off] = 0;
    }

    f32x4 acc[5];
    #pragma unroll
    for (int nf = 0; nf < 5; ++nf) acc[nf] = (f32x4){0.f, 0.f, 0.f, 0.f};

    for (int sub = 0; sub < 7; ++sub) {
        int n0 = chunk * 448 + sub * 64;
        #pragma unroll
        for (int li = 0; li < 4; ++li) {
            int idx = li * 256 + t;
            int row = idx >> 4, sc = idx & 15;
            int off = (row * 8 + ((sc >> 1) ^ (row & 7))) * 8 + (sc & 1) * 4;
            uint4 kf = *(const uint4*)&kp[(size_t)row * N_SP + n0 + sc * 4];
            ((uint*)&Kh[off])[0] = (kf.x & 0xFFFFu) | (kf.y << 16);
            ((uint*)&Kh[off])[1] = (kf.z & 0xFFFFu) | (kf.w << 16);
            ((uint*)&Kl[off])[0] = (kf.x >> 16) | (kf.y & 0xFFFF0000u);
            ((uint*)&Kl[off])[1] = (kf.z >> 16) | (kf.w & 0xFFFF0000u);
            float4 vf = *(const float4*)&vp[(size_t)row * N_SP + n0 + sc * 4];
            ushort h0,h1,h2,h3,l0,l1,l2,l3;
            bsplit(vf.x,h0,l0); bsplit(vf.y,h1,l1); bsplit(vf.z,h2,l2); bsplit(vf.w,h3,l3);
            ((uint*)&Vh[off])[0] = (uint)h0 | ((uint)h1 << 16);
            ((uint*)&Vh[off])[1] = (uint)h2 | ((uint)h3 << 16);
            ((uint*)&Vl[off])[0] = (uint)l0 | ((uint)l1 << 16);
            ((uint*)&Vl[off])[1] = (uint)l2 | ((uint)l3 << 16);
        }
        __syncthreads();
        #pragma unroll
        for (int s = 0; s < 2; ++s) {
            int arow = wv * 16 + l15;
            int akb = (s * 4 + lg) ^ (arow & 7);
            short8 ah = *(const short8*)&Kh[(arow * 8 + akb) * 8];
            short8 al = *(const short8*)&Kl[(arow * 8 + akb) * 8];
            #pragma unroll
            for (int nf = 0; nf < 5; ++nf) {
                int brow = nf * 16 + l15;
                int bkb = (s * 4 + lg) ^ (brow & 7);
                short8 bh = *(const short8*)&Vh[(brow * 8 + bkb) * 8];
                short8 bl = *(const short8*)&Vl[(brow * 8 + bkb) * 8];
                acc[nf] = __builtin_amdgcn_mfma_f32_16x16x32_bf16(ah, bh, acc[nf], 0, 0, 0);
                acc[nf] = __builtin_amdgcn_mfma_f32_16x16x32_bf16(ah, bl, acc[nf], 0, 0, 0);
                acc[nf] = __builtin_amdgcn_mfma_f32_16x16x32_bf16(al, bh, acc[nf], 0, 0, 0);
            }
        }
        __syncthreads();
    }

    size_t base = (size_t)((b*6 + h)*7 + chunk) * 64 * 80;
    #pragma unroll
    for (int nf = 0; nf < 5; ++nf)
        #pragma unroll
        for (int r = 0; r < 4; ++r) {
            int d = wv * 16 + lg * 4 + r;
            kv_part[base + (size_t)d * 80 + nf * 16 + l15] = acc[nf][r];
        }
}

// ---------------- K2b: reduce partials -> kv fp32 [bh][d][e] + km fp32 [bh][d].
__global__ __launch_bounds__(256) void k2b_reduce(
    const float* __restrict__ kv_part,
    float* __restrict__ kvf, float* __restrict__ km)
{
    const int bh = blockIdx.x;       // 96
    const int t = threadIdx.x;
    const float inv_n = 1.0f / (float)N_SP;
    const float* base = kv_part + (size_t)bh * 7 * 5120;
    float s[20];
    #pragma unroll
    for (int j = 0; j < 20; ++j) s[j] = 0.f;
    for (int c = 0; c < 7; ++c) {
        #pragma unroll
        for (int j = 0; j < 20; ++j) s[j] += base[c * 5120 + j * 256 + t];
    }
    #pragma unroll
    for (int j = 0; j < 20; ++j) {
        int i = j * 256 + t;
        int d = i / 80, e = i % 80;
        float v = s[j] * inv_n;
        if (e < 64)       kvf[(size_t)bh * 4096 + d * 64 + e] = v;
        else if (e == 64) km[bh * 64 + d] = v;
    }
}

// ---------------- K3: fused attn (fp32 VALU dot) + conv + BN, pure stream (no LDS/barriers).
// Grid (49, 6, 16); 4 waves/block; lane = pixel, wave = 16-channel slice.
__global__ __launch_bounds__(256) void k3_stream(
    const float* __restrict__ qbuf, const float* __restrict__ kvf,
    const float* __restrict__ km, const float* __restrict__ x,
    const float* __restrict__ pwsc, const float* __restrict__ psh,
    float* __restrict__ out)
{
    const int bx = blockIdx.x;
    const int h = blockIdx.y, b = blockIdx.z;
    const int t = threadIdx.x;
    const int lam = t & 63;
    const int w = t >> 6;
    const int n = bx * 64 + lam;
    const int ebase = w * 16;

    const float* qp  = qbuf + (size_t)(b * 384 + h * 64) * N_SP + n;
    const float* kvp = kvf + (size_t)(b * 6 + h) * 4096 + ebase;
    const float* kmp = km + (b * 6 + h) * 64;

    float acc[16];
    #pragma unroll
    for (int e = 0; e < 16; ++e) acc[e] = 0.f;
    float den = 0.f;

    #pragma unroll 4
    for (int d = 0; d < 64; ++d) {
        float qd = qp[(size_t)d * N_SP];
        den += qd * kmp[d];
        const float* kr = kvp + d * 64;
        #pragma unroll
        for (int eq = 0; eq < 4; ++eq) {
            float4 k4 = *(const float4*)(kr + eq * 4);
            acc[eq * 4 + 0] += qd * k4.x;
            acc[eq * 4 + 1] += qd * k4.y;
            acc[eq * 4 + 2] += qd * k4.z;
            acc[eq * 4 + 3] += qd * k4.w;
        }
    }
    const float r = 1.0f / (den + 1e-6f);

    const int y = n / 56, xc = n % 56;
    const bool xlo = (xc > 0), xhi = (xc < 55);
    #pragma unroll
    for (int e = 0; e < 16; ++e) {
        int c = h * 64 + ebase + e;
        const float* xp = x + ((size_t)b * 384 + c) * N_SP;
        const float* wp = pwsc + c * 9;
        float conv = 0.f;
        #pragma unroll
        for (int dy = 0; dy < 3; ++dy) {
            int yy = y + dy - 1;
            bool yok = (yy >= 0) && (yy < 56);
            const float* xr = xp + yy * 56 + xc;
            float t0 = (yok && xlo) ? xr[-1] : 0.f;
            float t1 = yok ? xr[0] : 0.f;
            float t2 = (yok && xhi) ? xr[1] : 0.f;
            conv += wp[dy * 3 + 0] * t0 + wp[dy * 3 + 1] * t1 + wp[dy * 3 + 2] * t2;
        }
        out[((size_t)b * 384 + c) * N_SP + n] = acc[e] * r + conv + psh[c];
    }
}

extern "C" void kernel_launch(void* const* d_in, const int* in_sizes, int n_in,
                              void* d_out, int out_size, void* d_ws, size_t ws_size,
                              hipStream_t stream)
{
    const float* x        = (const float*)d_in[0];
    const float* qk_w     = (const float*)d_in[1];
    const float* qk_gamma = (const float*)d_in[2];
    const float* qk_beta  = (const float*)d_in[3];
    const float* qk_mean  = (const float*)d_in[4];
    const float* qk_var   = (const float*)d_in[5];
    const float* pe_w     = (const float*)d_in[6];
    const float* pe_gamma = (const float*)d_in[7];
    const float* pe_beta  = (const float*)d_in[8];
    const float* pe_mean  = (const float*)d_in[9];
    const float* pe_var   = (const float*)d_in[10];
    float* out = (float*)d_out;

    float* ws      = (float*)d_ws;
    uint* kq       = (uint*)ws;
    float* qbuf    = ws + QB_OFF;
    float* kv_part = ws + KVP_OFF;
    float* kvf     = ws + KVF_OFF;
    float* km      = ws + KM_OFF;
    ushort* whp    = (ushort*)(ws + WH_OFF);
    ushort* wlp    = whp + WSPLIT_N;
    float* pwsc    = ws + PWS_OFF;
    float* psh     = ws + PSH_OFF;

    hipLaunchKernelGGL(p0_prep, dim3((WSPLIT_N + 255)/256), dim3(256), 0, stream,
                       qk_w, pe_w, pe_gamma, pe_beta, pe_mean, pe_var,
                       whp, wlp, pwsc, psh);
    dim3 g1(49, 3, 32);   // bz slowest: per-(b,g) x-slice L3-hot across the 3 o-tiles
    hipLaunchKernelGGL(k1_qk_mfma, g1, dim3(256), 0, stream,
                       x, whp, wlp, qk_gamma, qk_beta, qk_mean, qk_var, kq, qbuf);
    dim3 g2(7, 6, 16);
    hipLaunchKernelGGL(k2_kv_mfma, g2, dim3(256), 0, stream, x, kq, kv_part);
    hipLaunchKernelGGL(k2b_reduce, dim3(96), dim3(256), 0, stream,
                       kv_part, kvf, km);
    dim3 g3(49, 6, 16);
    hipLaunchKernelGGL(k3_stream, g3, dim3(256), 0, stream,
                       qbuf, kvf, km, x, pwsc, psh, out);
}

// Round 12
// 213.270 us; speedup vs baseline: 1.5237x; 1.5237x over previous
//
#include <hip/hip_runtime.h>
#include <math.h>

#define N_SP 3136
#define BN_EPS 1e-5f

typedef __attribute__((ext_vector_type(8))) short short8;
typedef __attribute__((ext_vector_type(4))) float f32x4;

// ws layout (float elements)
#define K_SZ    (16*384*N_SP)            // kq packed u32 (k, bf16 hi|lo<<16)
#define QB_OFF  (K_SZ)                   // qbuf fp32 [b][384][n]
#define QB_SZ   (16*384*N_SP)
#define KVP_OFF (QB_OFF + QB_SZ)
#define KVP_SZ  (16*6*7*64*80)           // per-chunk partials [d][80]
#define KVF_OFF (KVP_OFF + KVP_SZ)
#define KVF_SZ  (16*6*64*64)             // kv fp32 [bh][d][e]
#define KM_OFF  (KVF_OFF + KVF_SZ)
#define KM_SZ   (16*6*64)
#define WH_OFF  (KM_OFF + KM_SZ)         // wh/wl ushort planes
#define WSPLIT_N (2*384*192)
#define PWS_OFF (WH_OFF + WSPLIT_N)      // pwsc 384*9
#define PSH_OFF (PWS_OFF + 384*9)

// both-sides LDS swizzle for k1 B tile
#define FSWZ(n) ((((n) >> 1) ^ ((n) >> 2)) & 7)

__device__ __forceinline__ void bsplit(float f, ushort& h, ushort& l) {
    uint u = __float_as_uint(f);
    uint hr = (u + 0x7FFFu + ((u >> 16) & 1u)) >> 16;
    h = (ushort)hr;
    float fh = __uint_as_float(hr << 16);
    float fl = f - fh;
    uint v = __float_as_uint(fl);
    l = (ushort)((v + 0x7FFFu + ((v >> 16) & 1u)) >> 16);
}

// ---------------- P0: split qk_w into bf16 hi/lo planes; pre-scale pe weights/BN.
__global__ __launch_bounds__(256) void p0_prep(
    const float* __restrict__ qk_w, const float* __restrict__ pe_w,
    const float* __restrict__ pgamma, const float* __restrict__ pbeta,
    const float* __restrict__ pmean, const float* __restrict__ pvar,
    ushort* __restrict__ wh, ushort* __restrict__ wl,
    float* __restrict__ pwsc, float* __restrict__ psh)
{
    int idx = blockIdx.x * 256 + threadIdx.x;
    if (idx < WSPLIT_N) {
        ushort h, l;
        bsplit(qk_w[idx], h, l);
        wh[idx] = h;
        wl[idx] = l;
    }
    if (idx < 384) {
        float sc = pgamma[idx] / sqrtf(pvar[idx] + BN_EPS);
        psh[idx] = pbeta[idx] - pmean[idx] * sc;
        #pragma unroll
        for (int q = 0; q < 9; ++q) pwsc[idx * 9 + q] = pe_w[idx * 9 + q] * sc;
    }
}

// ---------------- K1: qk GEMM via bf16-split MFMA (R9 structure, measured 83us).
// gg=0 -> qbuf fp32; gg=1 -> kq packed u32.
__global__ __launch_bounds__(256) void k1_qk_mfma(
    const float* __restrict__ x, const ushort* __restrict__ wh, const ushort* __restrict__ wl,
    const float* __restrict__ gamma, const float* __restrict__ beta,
    const float* __restrict__ mean, const float* __restrict__ var,
    uint* __restrict__ kq, float* __restrict__ qbuf)
{
    __shared__ __align__(16) ushort Ah[8192];
    __shared__ __align__(16) ushort Al[8192];
    __shared__ __align__(16) ushort Bh[4096];
    __shared__ __align__(16) ushort Bl[4096];

    const int bx = blockIdx.x;           // 49 n-tiles
    const int by = blockIdx.y;           // 3 o-tiles (128 each)
    const int bz = blockIdx.z;           // b*2+g (slowest)
    const int b = bz >> 1, gg = bz & 1;
    const int t = threadIdx.x;
    const int lane = t & 63, wv = t >> 6;
    const int wr = wv >> 1, wc = wv & 1;
    const int lg = lane >> 4, l15 = lane & 15;

    f32x4 acc[4][2];
    #pragma unroll
    for (int m = 0; m < 4; ++m)
        #pragma unroll
        for (int nf = 0; nf < 2; ++nf)
            acc[m][nf] = (f32x4){0.f, 0.f, 0.f, 0.f};

    const float* xg = x + (size_t)(b * 384 + gg * 192) * N_SP + bx * 64;
    const ushort* whg = wh + (gg * 384 + by * 128) * 192;
    const ushort* wlg = wl + (gg * 384 + by * 128) * 192;

    for (int kt = 0; kt < 3; ++kt) {
        #pragma unroll
        for (int li = 0; li < 4; ++li) {
            int c = li * 256 + t;
            int row = c >> 3, kb = c & 7;
            int goff = row * 192 + kt * 64 + kb * 8;
            float4 vh = *(const float4*)(whg + goff);
            float4 vl = *(const float4*)(wlg + goff);
            int ch = (row * 8 + (kb ^ (row & 7))) * 8;
            *(float4*)&Ah[ch] = vh;
            *(float4*)&Al[ch] = vl;
        }
        #pragma unroll
        for (int li = 0; li < 2; ++li) {
            int idx = li * 256 + t;
            int kp = idx >> 4;
            int nq = idx & 15;
            int k0 = kp * 2;
            const float* px = xg + (size_t)(kt * 64 + k0) * N_SP + nq * 4;
            float4 v0 = *(const float4*)px;
            float4 v1 = *(const float4*)(px + N_SP);
            ushort h0[4], l0[4], h1[4], l1[4];
            float a0[4] = {v0.x, v0.y, v0.z, v0.w};
            float a1[4] = {v1.x, v1.y, v1.z, v1.w};
            #pragma unroll
            for (int i = 0; i < 4; ++i) { bsplit(a0[i], h0[i], l0[i]); bsplit(a1[i], h1[i], l1[i]); }
            int kb = k0 >> 3, ks = (k0 & 6) >> 1;
            #pragma unroll
            for (int i = 0; i < 4; ++i) {
                int n = nq * 4 + i;
                int chunk = n * 8 + (kb ^ FSWZ(n));
                ((uint*)Bh)[chunk * 4 + ks] = (uint)h0[i] | ((uint)h1[i] << 16);
                ((uint*)Bl)[chunk * 4 + ks] = (uint)l0[i] | ((uint)l1[i] << 16);
            }
        }
        __syncthreads();
        #pragma unroll
        for (int s = 0; s < 2; ++s) {
            short8 ah[4], al[4], bh[2], bl[2];
            int kb = s * 4 + lg;
            #pragma unroll
            for (int m = 0; m < 4; ++m) {
                int row = wr * 64 + m * 16 + l15;
                int ch = (row * 8 + (kb ^ (row & 7))) * 8;
                ah[m] = *(const short8*)&Ah[ch];
                al[m] = *(const short8*)&Al[ch];
            }
            #pragma unroll
            for (int nf = 0; nf < 2; ++nf) {
                int n = wc * 32 + nf * 16 + l15;
                int ch = (n * 8 + (kb ^ FSWZ(n))) * 8;
                bh[nf] = *(const short8*)&Bh[ch];
                bl[nf] = *(const short8*)&Bl[ch];
            }
            #pragma unroll
            for (int m = 0; m < 4; ++m)
                #pragma unroll
                for (int nf = 0; nf < 2; ++nf) {
                    acc[m][nf] = __builtin_amdgcn_mfma_f32_16x16x32_bf16(ah[m], bh[nf], acc[m][nf], 0, 0, 0);
                    acc[m][nf] = __builtin_amdgcn_mfma_f32_16x16x32_bf16(ah[m], bl[nf], acc[m][nf], 0, 0, 0);
                    acc[m][nf] = __builtin_amdgcn_mfma_f32_16x16x32_bf16(al[m], bh[nf], acc[m][nf], 0, 0, 0);
                }
        }
        __syncthreads();
    }

    float* scs = (float*)Bh;
    float* shs = scs + 128;
    if (t < 128) {
        int ch = gg * 384 + by * 128 + t;
        float sc = gamma[ch] / sqrtf(var[ch] + BN_EPS);
        scs[t] = sc;
        shs[t] = beta[ch] - mean[ch] * sc;
    }
    __syncthreads();

    size_t obase = ((size_t)b * 384 + by * 128) * N_SP + bx * 64 + wc * 32;
    if (gg == 0) {
        #pragma unroll
        for (int m = 0; m < 4; ++m)
            #pragma unroll
            for (int nf = 0; nf < 2; ++nf) {
                #pragma unroll
                for (int r = 0; r < 4; ++r) {
                    int orow = wr * 64 + m * 16 + lg * 4 + r;
                    float v = acc[m][nf][r] * scs[orow] + shs[orow];
                    v = v > 0.f ? v + 1.f : __expf(v);
                    qbuf[obase + (size_t)orow * N_SP + nf * 16 + l15] = v;
                }
            }
    } else {
        #pragma unroll
        for (int m = 0; m < 4; ++m)
            #pragma unroll
            for (int nf = 0; nf < 2; ++nf) {
                #pragma unroll
                for (int r = 0; r < 4; ++r) {
                    int orow = wr * 64 + m * 16 + lg * 4 + r;
                    float v = acc[m][nf][r] * scs[orow] + shs[orow];
                    v = v > 0.f ? v + 1.f : __expf(v);
                    ushort hh, ll;
                    bsplit(v, hh, ll);
                    kq[obase + (size_t)orow * N_SP + nf * 16 + l15] = (uint)hh | ((uint)ll << 16);
                }
            }
    }
}

// ---------------- K2: kv + ksum via MFMA; k from packed u32, v from fp32 x (unchanged).
__global__ __launch_bounds__(256) void k2_kv_mfma(
    const float* __restrict__ x, const uint* __restrict__ kq,
    float* __restrict__ kv_part)
{
    __shared__ __align__(16) ushort Kh[4096], Kl[4096];
    __shared__ __align__(16) ushort Vh[5120], Vl[5120];

    const int chunk = blockIdx.x;      // 7
    const int h = blockIdx.y, b = blockIdx.z;
    const int t = threadIdx.x;
    const int lane = t & 63, wv = t >> 6;
    const int lg = lane >> 4, l15 = lane & 15;

    const uint* kp  = kq + (size_t)(b*384 + h*64) * N_SP;
    const float* vp = x  + (size_t)(b*384 + h*64) * N_SP;

    #pragma unroll
    for (int li = 0; li < 4; ++li) {
        int idx = li * 256 + t;
        int row = 64 + (idx >> 6), col = idx & 63;
        int off = (row * 8 + ((col >> 3) ^ (row & 7))) * 8 + (col & 7);
        Vh[off] = (row == 64) ? (ushort)0x3F80 : (ushort)0;
        Vl[off] = 0;
    }

    f32x4 acc[5];
    #pragma unroll
    for (int nf = 0; nf < 5; ++nf) acc[nf] = (f32x4){0.f, 0.f, 0.f, 0.f};

    for (int sub = 0; sub < 7; ++sub) {
        int n0 = chunk * 448 + sub * 64;
        #pragma unroll
        for (int li = 0; li < 4; ++li) {
            int idx = li * 256 + t;
            int row = idx >> 4, sc = idx & 15;
            int off = (row * 8 + ((sc >> 1) ^ (row & 7))) * 8 + (sc & 1) * 4;
            uint4 kf = *(const uint4*)&kp[(size_t)row * N_SP + n0 + sc * 4];
            ((uint*)&Kh[off])[0] = (kf.x & 0xFFFFu) | (kf.y << 16);
            ((uint*)&Kh[off])[1] = (kf.z & 0xFFFFu) | (kf.w << 16);
            ((uint*)&Kl[off])[0] = (kf.x >> 16) | (kf.y & 0xFFFF0000u);
            ((uint*)&Kl[off])[1] = (kf.z >> 16) | (kf.w & 0xFFFF0000u);
            float4 vf = *(const float4*)&vp[(size_t)row * N_SP + n0 + sc * 4];
            ushort h0,h1,h2,h3,l0,l1,l2,l3;
            bsplit(vf.x,h0,l0); bsplit(vf.y,h1,l1); bsplit(vf.z,h2,l2); bsplit(vf.w,h3,l3);
            ((uint*)&Vh[off])[0] = (uint)h0 | ((uint)h1 << 16);
            ((uint*)&Vh[off])[1] = (uint)h2 | ((uint)h3 << 16);
            ((uint*)&Vl[off])[0] = (uint)l0 | ((uint)l1 << 16);
            ((uint*)&Vl[off])[1] = (uint)l2 | ((uint)l3 << 16);
        }
        __syncthreads();
        #pragma unroll
        for (int s = 0; s < 2; ++s) {
            int arow = wv * 16 + l15;
            int akb = (s * 4 + lg) ^ (arow & 7);
            short8 ah = *(const short8*)&Kh[(arow * 8 + akb) * 8];
            short8 al = *(const short8*)&Kl[(arow * 8 + akb) * 8];
            #pragma unroll
            for (int nf = 0; nf < 5; ++nf) {
                int brow = nf * 16 + l15;
                int bkb = (s * 4 + lg) ^ (brow & 7);
                short8 bh = *(const short8*)&Vh[(brow * 8 + bkb) * 8];
                short8 bl = *(const short8*)&Vl[(brow * 8 + bkb) * 8];
                acc[nf] = __builtin_amdgcn_mfma_f32_16x16x32_bf16(ah, bh, acc[nf], 0, 0, 0);
                acc[nf] = __builtin_amdgcn_mfma_f32_16x16x32_bf16(ah, bl, acc[nf], 0, 0, 0);
                acc[nf] = __builtin_amdgcn_mfma_f32_16x16x32_bf16(al, bh, acc[nf], 0, 0, 0);
            }
        }
        __syncthreads();
    }

    size_t base = (size_t)((b*6 + h)*7 + chunk) * 64 * 80;
    #pragma unroll
    for (int nf = 0; nf < 5; ++nf)
        #pragma unroll
        for (int r = 0; r < 4; ++r) {
            int d = wv * 16 + lg * 4 + r;
            kv_part[base + (size_t)d * 80 + nf * 16 + l15] = acc[nf][r];
        }
}

// ---------------- K2b: reduce partials -> kv fp32 [bh][d][e] + km fp32 [bh][d].
__global__ __launch_bounds__(256) void k2b_reduce(
    const float* __restrict__ kv_part,
    float* __restrict__ kvf, float* __restrict__ km)
{
    const int bh = blockIdx.x;       // 96
    const int t = threadIdx.x;
    const float inv_n = 1.0f / (float)N_SP;
    const float* base = kv_part + (size_t)bh * 7 * 5120;
    float s[20];
    #pragma unroll
    for (int j = 0; j < 20; ++j) s[j] = 0.f;
    for (int c = 0; c < 7; ++c) {
        #pragma unroll
        for (int j = 0; j < 20; ++j) s[j] += base[c * 5120 + j * 256 + t];
    }
    #pragma unroll
    for (int j = 0; j < 20; ++j) {
        int i = j * 256 + t;
        int d = i / 80, e = i % 80;
        float v = s[j] * inv_n;
        if (e < 64)       kvf[(size_t)bh * 4096 + d * 64 + e] = v;
        else if (e == 64) km[bh * 64 + d] = v;
    }
}

// ---------------- K3: fused attn + conv + BN (R4-proven structure, measured 106us).
// qs staged in LDS once; kv from global (L1-broadcast); tx->4px, ty->4ch; one barrier.
__global__ __launch_bounds__(256) void k3_attn_pe(
    const float* __restrict__ x, const float* __restrict__ qbuf,
    const float* __restrict__ kvf, const float* __restrict__ km,
    const float* __restrict__ pwsc, const float* __restrict__ psh,
    float* __restrict__ out)
{
    __shared__ float qs[64][68];   // [d][n]
    __shared__ float kms[64];
    const int bx = blockIdx.x;    // 49 n tiles
    const int h = blockIdx.y, b = blockIdx.z;
    const int t = threadIdx.x, tx = t & 15, ty = t >> 4;
    const int n0 = bx * 64;
    const float* qp  = qbuf + (size_t)(b * 384 + h * 64) * N_SP;
    const float* kvp = kvf + (size_t)(b * 6 + h) * 4096;
    #pragma unroll
    for (int l = 0; l < 4; ++l) {
        int idx = t + l * 256;
        int d = idx >> 4, c = idx & 15;
        *(float4*)&qs[d][c * 4] = *(const float4*)&qp[(size_t)d * N_SP + n0 + c * 4];
    }
    if (t < 64) kms[t] = km[(b * 6 + h) * 64 + t];
    __syncthreads();

    float acc[4][4] = {};   // [p=pixel][j=channel]
    float den[4] = {};
    #pragma unroll 8
    for (int d = 0; d < 64; ++d) {
        float4 qn = *(const float4*)&qs[d][tx * 4];       // 4 pixels (LDS)
        float4 ke = *(const float4*)&kvp[d * 64 + ty * 4]; // 4 channels (global, L1-hot)
        float qq[4] = {qn.x, qn.y, qn.z, qn.w}, kk[4] = {ke.x, ke.y, ke.z, ke.w};
        float kmd = kms[d];
        #pragma unroll
        for (int p = 0; p < 4; ++p) {
            den[p] += qq[p] * kmd;
            #pragma unroll
            for (int j = 0; j < 4; ++j) acc[p][j] += qq[p] * kk[j];
        }
    }

    // conv: pixels n0+tx*4..+3 lie in one image row (4 | 56); weights pre-scaled by BN
    const int p0 = n0 + tx * 4;
    const int y = p0 / 56, xc = p0 % 56;
    #pragma unroll
    for (int j = 0; j < 4; ++j) {
        int c = h * 64 + ty * 4 + j;
        const float* xp = x + ((size_t)b * 384 + c) * N_SP;
        float s6[3][6];
        #pragma unroll
        for (int dy = 0; dy < 3; ++dy) {
            int yy = y + dy - 1;
            bool yok = (yy >= 0) && (yy < 56);
            float4 mid = make_float4(0.f, 0.f, 0.f, 0.f);
            float lf = 0.f, rt = 0.f;
            if (yok) {
                const float* xr = xp + yy * 56;
                mid = *(const float4*)&xr[xc];
                if (xc > 0)  lf = xr[xc - 1];
                if (xc < 52) rt = xr[xc + 4];
            }
            s6[dy][0] = lf;  s6[dy][1] = mid.x; s6[dy][2] = mid.y;
            s6[dy][3] = mid.z; s6[dy][4] = mid.w; s6[dy][5] = rt;
        }
        float w9[9];
        #pragma unroll
        for (int q = 0; q < 9; ++q) w9[q] = pwsc[c * 9 + q];
        float sh2 = psh[c];
        float4 r;
        float* pr = (float*)&r;
        #pragma unroll
        for (int p = 0; p < 4; ++p) {
            float conv = 0.f;
            #pragma unroll
            for (int dy = 0; dy < 3; ++dy)
                #pragma unroll
                for (int dx = 0; dx < 3; ++dx)
                    conv += w9[dy * 3 + dx] * s6[dy][p + dx];
            pr[p] = acc[p][j] / (den[p] + 1e-6f) + conv + sh2;
        }
        *(float4*)&out[((size_t)b * 384 + c) * N_SP + p0] = r;
    }
}

extern "C" void kernel_launch(void* const* d_in, const int* in_sizes, int n_in,
                              void* d_out, int out_size, void* d_ws, size_t ws_size,
                              hipStream_t stream)
{
    const float* x        = (const float*)d_in[0];
    const float* qk_w     = (const float*)d_in[1];
    const float* qk_gamma = (const float*)d_in[2];
    const float* qk_beta  = (const float*)d_in[3];
    const float* qk_mean  = (const float*)d_in[4];
    const float* qk_var   = (const float*)d_in[5];
    const float* pe_w     = (const float*)d_in[6];
    const float* pe_gamma = (const float*)d_in[7];
    const float* pe_beta  = (const float*)d_in[8];
    const float* pe_mean  = (const float*)d_in[9];
    const float* pe_var   = (const float*)d_in[10];
    float* out = (float*)d_out;

    float* ws      = (float*)d_ws;
    uint* kq       = (uint*)ws;
    float* qbuf    = ws + QB_OFF;
    float* kv_part = ws + KVP_OFF;
    float* kvf     = ws + KVF_OFF;
    float* km      = ws + KM_OFF;
    ushort* whp    = (ushort*)(ws + WH_OFF);
    ushort* wlp    = whp + WSPLIT_N;
    float* pwsc    = ws + PWS_OFF;
    float* psh     = ws + PSH_OFF;

    hipLaunchKernelGGL(p0_prep, dim3((WSPLIT_N + 255)/256), dim3(256), 0, stream,
                       qk_w, pe_w, pe_gamma, pe_beta, pe_mean, pe_var,
                       whp, wlp, pwsc, psh);
    dim3 g1(49, 3, 32);
    hipLaunchKernelGGL(k1_qk_mfma, g1, dim3(256), 0, stream,
                       x, whp, wlp, qk_gamma, qk_beta, qk_mean, qk_var, kq, qbuf);
    dim3 g2(7, 6, 16);
    hipLaunchKernelGGL(k2_kv_mfma, g2, dim3(256), 0, stream, x, kq, kv_part);
    hipLaunchKernelGGL(k2b_reduce, dim3(96), dim3(256), 0, stream,
                       kv_part, kvf, km);
    dim3 g3(49, 6, 16);
    hipLaunchKernelGGL(k3_attn_pe, g3, dim3(256), 0, stream,
                       x, qbuf, kvf, km, pwsc, psh, out);
}